// Round 7
// baseline (1257.583 us; speedup 1.0000x reference)
//
#include <hip/hip_runtime.h>
#include <hip/hip_cooperative_groups.h>
#include <math.h>

namespace cg = cooperative_groups;

#define TT 96
#define BB 128
#define DD 800
#define LL 128

typedef _Float16 h2v __attribute__((ext_vector_type(2)));
typedef _Float16 f16x8 __attribute__((ext_vector_type(8)));
typedef float f32x4 __attribute__((ext_vector_type(4)));

// ---- ws layout (4B units), shared host/device ----
constexpr size_t O_WPX   = 0;                    // 102400 fp32
constexpr size_t O_WPR   = O_WPX   + 102400;     // 16384 uints (fdot2 pack)
constexpr size_t O_WEN   = O_WPR   + 16384;      // 16384 (out-half pack only)
constexpr size_t O_BFENX = O_WEN   + 32768;      // 16384 (MFMA B-frags W_en x-half)
constexpr size_t O_BFIZ  = O_BFENX + 16384;      // 32768 (MFMA B-frags W_ihz^T)
constexpr size_t O_BFHH  = O_BFIZ  + 32768;      // 32768 (MFMA B-frags W_hh^T)
constexpr size_t O_BFDE  = O_BFHH  + 32768;      // 102400 (MFMA B-frags W_de^T, K=256)
constexpr size_t O_BFPZ  = O_BFDE  + 102400;     // 8192 (MFMA B-frags W_pz^T)
constexpr size_t O_BL    = O_BFPZ  + 8192;       // 512
constexpr size_t O_ACC   = O_BL    + 512;        // 2 (double)
constexpr size_t O_PROG  = O_ACC   + 4;          // 128 ints (progress flags)
constexpr size_t O_XHAT  = O_PROG  + 128;        // (unused since R7; layout keep)
constexpr size_t O_GX    = O_XHAT  + 786432;     // 6291456 fp32 (gxh: 12288 x 512)
constexpr size_t O_ENCX  = O_GX    + 6291456;    // 3145728 fp32 (encx: 12288 x 256)
constexpr size_t O_OUT   = O_ENCX  + 3145728;    // 1572864 fp32
constexpr size_t O_Q2    = O_OUT   + 1572864;    // float2[12288*128] (muq,sgq)
constexpr size_t O_P2    = O_Q2    + 3145728;    // float2[12288*128] (mup,sgp)

__device__ __forceinline__ h2v u2h(unsigned u) {
  union { unsigned u; h2v h; } x; x.u = u; return x.h;
}
__device__ __forceinline__ float fdot2(unsigned w, unsigned v, float acc) {
  return __builtin_amdgcn_fdot2(u2h(w), u2h(v), acc, false);
}
__device__ __forceinline__ unsigned packf16(float a, float b) {
  union { _Float16 h[2]; unsigned u; } x;
  x.h[0] = (_Float16)a; x.h[1] = (_Float16)b;
  return x.u;
}
__device__ __forceinline__ f16x8 u4h8(uint4 u) {
  union { uint4 u; f16x8 h; } x; x.u = u; return x.h;
}
__device__ __forceinline__ f32x4 mfma16(uint4 a, uint4 b, f32x4 c) {
  return __builtin_amdgcn_mfma_f32_16x16x32_f16(u4h8(a), u4h8(b), c, 0, 0, 0);
}
__device__ __forceinline__ float frcp(float x) { return __builtin_amdgcn_rcpf(x); }
__device__ __forceinline__ float fsigm(float x) { return frcp(1.f + __expf(-x)); }
__device__ __forceinline__ float ftanh(float x) {
  float e = __expf(2.f * fabsf(x));
  float t = 1.f - 2.f * frcp(e + 1.f);
  return copysignf(t, x);
}
__device__ __forceinline__ float hsum4(float4 a) { return (a.x + a.y) + (a.z + a.w); }

__device__ __forceinline__ void dotacc4(uint4 wv, uint4 vv, float4& av) {
  av.x = fdot2(wv.x, vv.x, av.x);
  av.y = fdot2(wv.y, vv.y, av.y);
  av.z = fdot2(wv.z, vv.z, av.z);
  av.w = fdot2(wv.w, vv.w, av.w);
}

// raw LDS-only barrier (no vmcnt drain); sched_barrier fences per rule #18
__device__ __forceinline__ void bar_lds() {
  asm volatile("s_waitcnt lgkmcnt(0)" ::: "memory");
  __builtin_amdgcn_sched_barrier(0);
  __builtin_amdgcn_s_barrier();
  __builtin_amdgcn_sched_barrier(0);
}

// agent-scope stores/loads for cross-XCD producer->consumer handoff
__device__ __forceinline__ void gstore(float* p, float v) {
  __hip_atomic_store(p, v, __ATOMIC_RELAXED, __HIP_MEMORY_SCOPE_AGENT);
}
__device__ __forceinline__ float gload(const float* p) {
  return __hip_atomic_load(p, __ATOMIC_RELAXED, __HIP_MEMORY_SCOPE_AGENT);
}
__device__ __forceinline__ void gstore2(float2* p, float a, float b) {
  union { float f[2]; unsigned long long u; } x; x.f[0] = a; x.f[1] = b;
  __hip_atomic_store((unsigned long long*)p, x.u, __ATOMIC_RELAXED, __HIP_MEMORY_SCOPE_AGENT);
}
__device__ __forceinline__ float2 gload2(const float2* p) {
  unsigned long long u = __hip_atomic_load((const unsigned long long*)p,
                                           __ATOMIC_RELAXED, __HIP_MEMORY_SCOPE_AGENT);
  union { unsigned long long u; float2 f; } x; x.u = u; return x.f;
}

// consumer LDS XOR swizzle (T2)
__device__ __forceinline__ int swz128(int row, int col) {
  return row * 128 + (col ^ ((row & 7) << 3));
}
__device__ __forceinline__ int swz256(int row, int col) {
  return row * 256 + (col ^ ((row & 7) << 3));
}

// ---------------- prep bodies (grid-stride phase 0) ----------------
__device__ __forceinline__ void pack_f16_body(const float* __restrict__ src,
                                              unsigned* __restrict__ dst,
                                              int J, int rs, int k0, int idx) {
  int u = idx & 3;
  int t2 = idx >> 2;
  int k8 = t2 / J;
  int j = t2 - k8 * J;
  int k = k8 * 8 + u * 2;
  const float* r = src + (size_t)j * rs + k0 + k;
  dst[idx] = packf16(r[0], r[1]);
}

__device__ __forceinline__ void bfrag_body(const float* __restrict__ src,
                                           unsigned* __restrict__ dst,
                                           int rs, int k0, int KS, int mode, int idx) {
  int jj = idx & 3;
  int lane = (idx >> 2) & 63;
  int t2 = idx >> 8;
  int ks = t2 % KS;
  int g = t2 / KS;
  int n = (mode == 0) ? (128 * (g & 3) + 16 * (g >> 2) + (lane & 15))
                      : (16 * g + (lane & 15));
  int k = ks * 32 + (lane >> 4) * 8 + jj * 2;
  const float* r = src + (size_t)n * rs + k0 + k;
  dst[idx] = packf16(r[0], r[1]);
}

__device__ __forceinline__ void transpose_body(const float* __restrict__ src,
                                               float* __restrict__ dst,
                                               int J, int rs, int k0, int idx) {
  int J4 = J * 4;
  int k4 = idx / J4;
  int rem = idx - k4 * J4;
  int j = rem >> 2;
  int kk = rem & 3;
  dst[idx] = src[j * rs + k0 + k4 * 4 + kk];
}

__device__ __forceinline__ float dot4(float4 w, float4 v) {
  return w.x*v.x + w.y*v.y + w.z*v.z + w.w*v.w;
}

// ---------------- the ONE kernel ----------------
// Phase 0: grid-strided weight transforms (was prep_all).
// Phase A: per-block xhat tile (16 pairs, wave-uniform scalar x loads, no LDS
//   staging) -> packed f16 tile in LDS -> gxh/encx MFMA (was xhat + prep_gx;
//   xhat2 never touches global: its only consumer is this block's gx step).
// Phase B: R6 producer/consumer, byte-identical logic.
// Finalize: grid sync + block 0 writes out. Launch count: 5 -> 1.
// __threadfence() (agent scope: L2 wb/inv) brackets grid syncs for cross-XCD
// visibility of phase outputs.
__global__ __launch_bounds__(512) void mega_kernel(
    const float* __restrict__ x, const float* __restrict__ beta_p,
    const float* __restrict__ eps,
    const float* __restrict__ W_px, const float* __restrict__ b_px,
    const float* __restrict__ W_pz, const float* __restrict__ b_pz,
    const float* __restrict__ W_pr, const float* __restrict__ b_pr,
    const float* __restrict__ W_en, const float* __restrict__ b_en,
    const float* __restrict__ W_de, const float* __restrict__ b_de,
    const float* __restrict__ W_ih, const float* __restrict__ W_hh,
    const float* __restrict__ b_ih, const float* __restrict__ b_hh,
    float* __restrict__ ws, float* __restrict__ out)
{
  __shared__ __align__(16) char SMEM[161536];
  const int tid = threadIdx.x;
  const int bid = blockIdx.x;
  cg::grid_group grid = cg::this_grid();

  // derived ws pointers
  const uint4* Wpr4  = (const uint4*)(ws + O_WPR);
  const uint4* Wen4  = (const uint4*)(ws + O_WEN);
  const uint4* BFpz  = (const uint4*)(ws + O_BFPZ);
  const uint4* BFihz = (const uint4*)(ws + O_BFIZ);
  const uint4* BFhh  = (const uint4*)(ws + O_BFHH);
  const uint4* BFde  = (const uint4*)(ws + O_BFDE);
  const float* gxh_g  = ws + O_GX;
  const float* encx_g = ws + O_ENCX;
  float* g_out = ws + O_OUT;
  float2* g_q2 = (float2*)(ws + O_Q2);
  float2* g_p2 = (float2*)(ws + O_P2);
  double* accum = (double*)(ws + O_ACC);
  int* prog = (int*)(ws + O_PROG);

  // ================= phase 0: weight transforms =================
  if (bid == 0) {
    if (tid == 0) *accum = 0.0;
    if (tid < 128)
      __hip_atomic_store(&prog[tid], 0, __ATOMIC_RELAXED, __HIP_MEMORY_SCOPE_AGENT);
  }
  for (int it = bid * 512 + tid; it < 328192; it += 131072) {
    if (it < 512)         ws[O_BL + it] = b_ih[it] + b_hh[it];
    else if (it < 16896)  pack_f16_body(W_pr, (unsigned*)(ws + O_WPR), 256, 128, 0, it - 512);
    else if (it < 33280)  pack_f16_body(W_en, (unsigned*)(ws + O_WEN), 256, 256, 0, it - 16896);
    else if (it < 49664)  bfrag_body(W_en, (unsigned*)(ws + O_BFENX), 256, 128, 4, 1, it - 33280);
    else if (it < 82432)  bfrag_body(W_ih, (unsigned*)(ws + O_BFIZ), 256, 128, 4, 0, it - 49664);
    else if (it < 115200) bfrag_body(W_hh, (unsigned*)(ws + O_BFHH), 128, 0, 4, 0, it - 82432);
    else if (it < 123392) bfrag_body(W_pz, (unsigned*)(ws + O_BFPZ), 128, 0, 4, 1, it - 115200);
    else if (it < 225792) bfrag_body(W_de, (unsigned*)(ws + O_BFDE), 256, 0, 8, 1, it - 123392);
    else                  transpose_body(W_px, ws + O_WPX, 128, 800, 0, it - 225792);
  }
  __threadfence();
  grid.sync();

  // ================= phase A: xhat -> gxh/encx, tile-local =================
  {
    unsigned* s_xh = (unsigned*)SMEM;        // [16*68] padded (4352B)
    const float4* W = (const float4*)(ws + O_WPX);
    const int j = tid & 127, g = tid >> 7;   // g uniform per wave (wave>>1)
    const int wv = tid >> 6, lane = tid & 63, l15 = lane & 15, quad = lane >> 4;
    const float bj = b_px[j];

    for (int i = 0; i < 3; ++i) {
      const int tx = bid + 256 * i;          // 768 tiles
      const int p0 = tx * 16;
      // xhat for rows g+4u: x addresses wave-uniform -> scalar (K$) loads
      int offs[4];
      #pragma unroll
      for (int u = 0; u < 4; ++u) {
        int p = p0 + g + 4 * u;
        int b_ = p & 127, t_ = p >> 7;
        offs[u] = __builtin_amdgcn_readfirstlane((b_ * TT + t_) * 800);
      }
      float acc[4];
      #pragma unroll
      for (int u = 0; u < 4; ++u) acc[u] = bj;
      #pragma unroll 2
      for (int k4 = 0; k4 < 200; ++k4) {
        float4 w = W[k4 * 128 + j];
        #pragma unroll
        for (int u = 0; u < 4; ++u) {
          float4 xv = *(const float4*)(x + offs[u] + k4 * 4);
          acc[u] += dot4(w, xv);
        }
      }
      #pragma unroll
      for (int u = 0; u < 4; ++u) {
        float v = fmaxf(acc[u], 0.f);
        float vp = __shfl_xor(v, 1, 64);
        if ((j & 1) == 0)
          s_xh[(g + 4 * u) * 68 + (j >> 1)] = packf16(v, vp);
      }
      __syncthreads();

      // gx: A-frags from LDS tile; gxh 4 tiles + encx 2 tiles per wave
      uint4 a[4];
      #pragma unroll
      for (int ks = 0; ks < 4; ++ks)
        a[ks] = *(const uint4*)&s_xh[l15 * 68 + ks * 16 + quad * 4];
      #pragma unroll
      for (int nt = 0; nt < 4; ++nt) {
        int gg = wv * 4 + nt;
        int n = 128 * (gg & 3) + 16 * (gg >> 2) + l15;
        float bl = ws[O_BL + n];
        f32x4 acc2 = {0.f, 0.f, 0.f, 0.f};
        #pragma unroll
        for (int ks = 0; ks < 4; ++ks)
          acc2 = mfma16(a[ks], BFihz[(gg * 4 + ks) * 64 + lane], acc2);
        #pragma unroll
        for (int r = 0; r < 4; ++r)
          ws[O_GX + (size_t)(p0 + quad * 4 + r) * 512 + n] = acc2[r] + bl;
      }
      #pragma unroll
      for (int gt = 0; gt < 2; ++gt) {
        int gg = wv * 2 + gt;
        f32x4 acc2 = {0.f, 0.f, 0.f, 0.f};
        #pragma unroll
        for (int ks = 0; ks < 4; ++ks)
          acc2 = mfma16(a[ks], ((const uint4*)(ws + O_BFENX))[(gg * 4 + ks) * 64 + lane], acc2);
        #pragma unroll
        for (int r = 0; r < 4; ++r)
          ws[O_ENCX + (size_t)(p0 + quad * 4 + r) * 256 + 16 * gg + l15] = acc2[r];
      }
      __syncthreads();
    }
  }
  __threadfence();
  grid.sync();

  // ================= phase B: producer / consumer (R6 logic) =================
  if (bid < 128) {
    // ---------------- producer ----------------
    float* s_gz       = (float*)SMEM;               // [5120] gate pre-acts
    float* s_ehmu     = (float*)SMEM;               // [128] aliases gz[0:128]
    float* s_mup      = (float*)(SMEM + 512);       // [128]
    float* s_sgp      = (float*)(SMEM + 1024);      // [128]
    float* s_sgq      = (float*)(SMEM + 1536);      // [128]
    _Float16* s_z2    = (_Float16*)(SMEM + 20480);  // [16*136]
    _Float16* s_zh2   = (_Float16*)(SMEM + 24832);  // [16*136]
    float* s_out      = (float*)(SMEM + 29184);     // [128]
    unsigned* s_out2  = (unsigned*)(SMEM + 29696);  // [64]
    _Float16* s_h2    = (_Float16*)(SMEM + 29952);  // [2][128]
    uint4* s_bfihz    = (uint4*)(SMEM + 30464);     // [8192] (131072B)

    const int b = bid;
    const int wv = tid >> 6;
    const int lane = tid & 63;
    const int l15 = lane & 15;
    const int quad = lane >> 4;

    // one-time: stage BFihz into LDS (16 uint4/thread, coalesced)
    #pragma unroll
    for (int i = 0; i < 16; ++i)
      s_bfihz[i * 512 + tid] = BFihz[i * 512 + tid];

    if (tid < 128) { s_out[tid] = 0.f; s_h2[tid] = (_Float16)0.f; }
    if (tid < 64) s_out2[tid] = 0u;
    float c_reg = 0.f;
    const float bias_pe = (tid < 256) ? b_pr[tid] : b_en[tid - 256];
    const float bz = b_pz[16 * wv + l15];
    const int gxoff = 16 * wv + l15;

    uint4 whhf[16], bfpz[4];
    #pragma unroll
    for (int i = 0; i < 16; ++i) whhf[i] = BFhh[(wv * 16 + i) * 64 + lane];
    #pragma unroll
    for (int ks = 0; ks < 4; ++ks) bfpz[ks] = BFpz[(wv * 4 + ks) * 64 + lane];

    // t=0 preloads (eps, gx, encx)
    float e0 = eps[(size_t)b * 1280 + tid];
    float e1 = eps[(size_t)b * 1280 + tid + 512];
    float e2 = (tid < 256) ? eps[(size_t)b * 1280 + tid + 1024] : 0.f;
    float gxf[4];
    #pragma unroll
    for (int nt = 0; nt < 4; ++nt)
      gxf[nt] = gxh_g[(size_t)b * 512 + 128 * nt + gxoff];
    float encx_r = (tid >= 256) ? encx_g[(size_t)b * 256 + (tid - 256)] : 0.f;

    __syncthreads();

    for (int t = 0; t < TT; ++t) {
      const size_t pb = (size_t)t * BB + b;

      // S1: prior (tid<256) / encoder (tid>=256) GEMV
      {
        float4 a4 = {bias_pe, 0.f, 0.f, 0.f};
        if (tid < 256) {
          #pragma unroll 4
          for (int k8 = 0; k8 < 16; ++k8) {
            uint4 w = Wpr4[k8 * 256 + tid];
            uint4 o = *(const uint4*)&s_out2[k8 * 4];
            dotacc4(w, o, a4);
          }
          float ph = fmaxf(hsum4(a4), 0.f);
          if (tid < 128) s_mup[tid] = ph;
          else {
            float y = __expf(ph) + 0.5f;
            float sp = (y > 20.f) ? y : __logf(1.f + __expf(y));
            s_sgp[tid - 128] = sp;
          }
        } else {
          int j2 = tid - 256;
          #pragma unroll 4
          for (int k8 = 0; k8 < 16; ++k8) {
            uint4 w = Wen4[k8 * 256 + j2];
            uint4 o = *(const uint4*)&s_out2[k8 * 4];
            dotacc4(w, o, a4);
          }
          float eh = fmaxf(hsum4(a4) + encx_r, 0.f);
          if (j2 < 128) s_ehmu[j2] = eh;
          else s_sgq[j2 - 128] = __expf(eh);
        }
      }
      bar_lds();                             // B2

      // S2: z into padded s_z2 rows (sample = row)
      {
        int l = tid & 127, s0 = tid >> 7;
        float mu = s_ehmu[l] + s_mup[l];
        float sq = s_sgq[l];
        s_z2[s0 * 136 + l]        = (_Float16)(mu + sq * e0);
        s_z2[(s0 + 4) * 136 + l]  = (_Float16)(mu + sq * e1);
        if (tid < 256) s_z2[(s0 + 8) * 136 + l] = (_Float16)(mu + sq * e2);
      }
      bar_lds();                             // B3

      // batched sc1 publication of timestep t; drains at B5's full sync
      if (tid < 128) {
        gstore2(&g_q2[pb * 128 + tid], s_ehmu[tid] + s_mup[tid], s_sgq[tid]);
      } else if (tid < 256) {
        gstore(&g_out[pb * 128 + tid - 128], s_out[tid - 128]);
      } else if (tid < 384) {
        int l = tid - 256;
        gstore2(&g_p2[pb * 128 + l], s_mup[l], s_sgp[l]);
      }

      // S3: z_hat via MFMA
      {
        uint4 a[4];
        #pragma unroll
        for (int ks = 0; ks < 4; ++ks)
          a[ks] = *(const uint4*)&s_z2[l15 * 136 + ks * 32 + quad * 8];
        f32x4 acc = {bz, bz, bz, bz};
        #pragma unroll
        for (int ks = 0; ks < 4; ++ks)
          acc = mfma16(a[ks], bfpz[ks], acc);
        #pragma unroll
        for (int r = 0; r < 4; ++r) {
          int s = quad * 4 + r;
          if (s < 10)
            s_zh2[s * 136 + 16 * wv + l15] = (_Float16)fmaxf(acc[r], 0.f);
        }
      }
      bar_lds();                             // B4

      // S4: gates-z via MFMA; B-frags from LDS, init from precomputed gxf
      {
        uint4 a[4];
        #pragma unroll
        for (int ks = 0; ks < 4; ++ks)
          a[ks] = *(const uint4*)&s_zh2[l15 * 136 + ks * 32 + quad * 8];
        #pragma unroll
        for (int nt = 0; nt < 4; ++nt) {
          float gx = gxf[nt];
          f32x4 acc = {gx, gx, gx, gx};
          #pragma unroll
          for (int ks = 0; ks < 4; ++ks)
            acc = mfma16(a[ks], s_bfihz[((wv * 4 + nt) * 4 + ks) * 64 + lane], acc);
          #pragma unroll
          for (int r = 0; r < 4; ++r) {
            int s = quad * 4 + r;
            if (s < 10)
              s_gz[s * 512 + 128 * nt + 16 * wv + l15] = acc[r];
          }
        }
      }
      __syncthreads();                       // B5 FULL: drains g_* sc1 stores + orders s_gz

      if (tid == 0)
        __hip_atomic_store(&prog[b], t + 1, __ATOMIC_RELAXED, __HIP_MEMORY_SCOPE_AGENT);

      // t+1 prefetch under the LSTM
      if (t + 1 < TT) {
        const float* epn = eps + (pb + BB) * 1280;
        e0 = epn[tid];
        e1 = epn[tid + 512];
        if (tid < 256) e2 = epn[tid + 1024];
        #pragma unroll
        for (int nt = 0; nt < 4; ++nt)
          gxf[nt] = gxh_g[(pb + BB) * 512 + 128 * nt + gxoff];
        if (tid >= 256) encx_r = encx_g[(pb + BB) * 256 + (tid - 256)];
      }

      // serial LSTM over 10 samples, double-buffered h
      float oacc = 0.f;
      for (int s = 0; s < 10; ++s) {
        const _Float16* hb = &s_h2[(s & 1) * 128];
        uint4 a[4];
        #pragma unroll
        for (int ks = 0; ks < 4; ++ks)
          a[ks] = *(const uint4*)&hb[ks * 32 + quad * 8];
        f32x4 acc[4];
        #pragma unroll
        for (int nt = 0; nt < 4; ++nt) {
          float cz = s_gz[s * 512 + 128 * nt + 16 * wv + l15];
          acc[nt] = f32x4{cz, cz, cz, cz};
        }
        #pragma unroll
        for (int nt = 0; nt < 4; ++nt)
          #pragma unroll
          for (int ks = 0; ks < 4; ++ks)
            acc[nt] = mfma16(a[ks], whhf[nt * 4 + ks], acc[nt]);
        if (lane < 16) {
          float gi = acc[0][0], gf = acc[1][0], gg = acc[2][0], go = acc[3][0];
          c_reg = fsigm(gf) * c_reg + fsigm(gi) * ftanh(gg);
          float h = fsigm(go) * ftanh(c_reg);
          oacc += h;
          s_h2[((s + 1) & 1) * 128 + 16 * wv + lane] = (_Float16)h;
        }
        if (s < 9) bar_lds();
      }
      if (lane < 16) {
        float v = oacc * 0.1f;
        s_out[16 * wv + lane] = v;
        float vn = __shfl_xor(v, 1, 64);
        if (!(lane & 1)) s_out2[8 * wv + (lane >> 1)] = packf16(v, vn);
      }
      bar_lds();
    }
  } else {
    // ---------------- consumer ----------------
    _Float16* c_z2   = (_Float16*)SMEM;             // [48*128] swizzled
    _Float16* c_a2   = (_Float16*)(SMEM + 12288);   // [48*256] swizzled
    float* c_x       = (float*)(SMEM + 36864);      // [4*800]
    unsigned* c_out2 = (unsigned*)(SMEM + 49664);   // [256]
    float* c_muq     = (float*)(SMEM + 50688);      // [512]
    float* c_sgq     = (float*)(SMEM + 52736);
    float* c_mup     = (float*)(SMEM + 54784);
    float* c_sgp     = (float*)(SMEM + 56832);
    float* c_wred    = (float*)(SMEM + 58880);      // [8]

    const int cid = bid - 128;
    const int wv = tid >> 6;
    const int lane = tid & 63;
    const int l15 = lane & 15;
    const int quad = lane >> 4;
    const float beta = beta_p[0];

    for (int c = cid; c < 3072; c += 128) {
      const int p0 = c * 4;
      const int t = p0 >> 7;
      const int b0 = p0 & 127;

      if (tid < 4) {
        while (__hip_atomic_load(&prog[b0 + tid], __ATOMIC_RELAXED,
                                 __HIP_MEMORY_SCOPE_AGENT) <= t)
          __builtin_amdgcn_s_sleep(8);
      }
      __syncthreads();

      float acc_loc = 0.f;
      {
        size_t gi = (size_t)p0 * 128 + tid;
        float2 q = gload2(&g_q2[gi]); c_muq[tid] = q.x; c_sgq[tid] = q.y;
        float2 pv = gload2(&g_p2[gi]); c_mup[tid] = pv.x; c_sgp[tid] = pv.y;
      }
      if (tid < 256) {
        int pair = tid >> 6, m = tid & 63;
        const float* o = g_out + (size_t)p0 * 128 + pair * 128;
        c_out2[tid] = packf16(gload(o + 2*m), gload(o + 2*m + 1));
      }
      for (int i = tid; i < 3200; i += 512) {
        int pp = i / 800;
        int d = i - pp * 800;
        int p = p0 + pp, bb = p & 127, tt2 = p >> 7;
        c_x[i] = x[((size_t)bb * TT + tt2) * 800 + d];
      }
      __syncthreads();

      // z + KL
      {
        int l = tid & 127, pp = tid >> 7;
        float mq = c_muq[pp*128 + l], sq = c_sgq[pp*128 + l];
        float mp = c_mup[pp*128 + l], spv = c_sgp[pp*128 + l];
        float inv_sp = frcp(spv);
        float lsq = __logf(sq), lsp = __logf(spv);
        const float* ep = eps + (size_t)(p0 + pp) * 1280 + l;
        float kl = 0.f;
        #pragma unroll
        for (int s = 0; s < 10; ++s) {
          float e = ep[s * 128];
          float z = mq + sq * e;
          c_z2[swz128(pp * 10 + s, l)] = (_Float16)z;
          float ap = (z - mp) * inv_sp;
          kl += (-0.5f * e * e - lsq) - (-0.5f * ap * ap - lsp);
        }
        acc_loc -= beta * kl;
      }
      for (int i = tid; i < 2560; i += 512) {
        int r = i >> 6, m = i & 63;
        int pp = (r * 205) >> 11;
        ((unsigned*)c_a2)[r * 128 + 64 + (m ^ ((r & 7) << 2))] = c_out2[pp * 64 + m];
      }
      __syncthreads();

      // z_hat via MFMA: M=48(40 used) N=128 K=128
      for (int tile = wv; tile < 24; tile += 8) {
        int mt = tile >> 3, nt = tile & 7;
        uint4 a[4];
        #pragma unroll
        for (int ks = 0; ks < 4; ++ks)
          a[ks] = *(const uint4*)&c_z2[swz128(mt * 16 + l15, ks * 32 + quad * 8)];
        float bzt = b_pz[16 * nt + l15];
        f32x4 acc = {bzt, bzt, bzt, bzt};
        #pragma unroll
        for (int ks = 0; ks < 4; ++ks)
          acc = mfma16(a[ks], BFpz[(nt * 4 + ks) * 64 + lane], acc);
        #pragma unroll
        for (int r = 0; r < 4; ++r) {
          int row = mt * 16 + quad * 4 + r;
          c_a2[swz256(row, 16 * nt + l15)] = (_Float16)fmaxf(acc[r], 0.f);
        }
      }
      __syncthreads();

      // decoder GEMM + Bernoulli epilogue
      #pragma unroll
      for (int mt = 0; mt < 3; ++mt) {
        uint4 a[8];
        #pragma unroll
        for (int ks = 0; ks < 8; ++ks)
          a[ks] = *(const uint4*)&c_a2[swz256(mt * 16 + l15, ks * 32 + quad * 8)];
        for (int nt = wv; nt < 50; nt += 8) {
          f32x4 acc = {0.f, 0.f, 0.f, 0.f};
          #pragma unroll
          for (int ks = 0; ks < 8; ++ks)
            acc = mfma16(a[ks], BFde[(nt * 8 + ks) * 64 + lane], acc);
          int d = 16 * nt + l15;
          float bd = b_de[d];
          #pragma unroll
          for (int r = 0; r < 4; ++r) {
            int row = mt * 16 + quad * 4 + r;
            if (row < 40) {
              int pp = (row * 205) >> 11;
              float lg = fmaxf(acc[r] + bd, 0.f);
              float xd = c_x[pp * 800 + d];
              acc_loc += xd * lg - lg - __logf(1.f + __expf(-lg));
            }
          }
        }
      }

      float v = acc_loc;
      #pragma unroll
      for (int off = 32; off > 0; off >>= 1) v += __shfl_down(v, off, 64);
      if ((tid & 63) == 0) c_wred[tid >> 6] = v;
      __syncthreads();
      if (tid == 0) {
        double tot = 0.0;
        #pragma unroll
        for (int w = 0; w < 8; ++w) tot += (double)c_wred[w];
        atomicAdd(accum, tot);
      }
      __syncthreads();
    }
  }

  // ================= finalize =================
  __threadfence();
  grid.sync();
  if (bid == 0 && tid == 0) {
    double a = *(volatile double*)accum;
    out[0] = (float)(-a / 122880.0);   // B*T*S
  }
}

// ---------------- host ----------------
extern "C" void kernel_launch(void* const* d_in, const int* in_sizes, int n_in,
                              void* d_out, int out_size, void* d_ws, size_t ws_size,
                              hipStream_t stream) {
  const float* x    = (const float*)d_in[0];
  const float* beta = (const float*)d_in[1];
  const float* eps  = (const float*)d_in[2];
  const float* W_px = (const float*)d_in[3];
  const float* b_px = (const float*)d_in[4];
  const float* W_pz = (const float*)d_in[5];
  const float* b_pz = (const float*)d_in[6];
  const float* W_pr = (const float*)d_in[7];
  const float* b_pr = (const float*)d_in[8];
  const float* W_en = (const float*)d_in[9];
  const float* b_en = (const float*)d_in[10];
  const float* W_de = (const float*)d_in[11];
  const float* b_de = (const float*)d_in[12];
  const float* W_ih = (const float*)d_in[13];
  const float* W_hh = (const float*)d_in[14];
  const float* b_ih = (const float*)d_in[15];
  const float* b_hh = (const float*)d_in[16];
  float* ws = (float*)d_ws;
  float* out = (float*)d_out;

  void* kargs[] = {
    (void*)&x, (void*)&beta, (void*)&eps,
    (void*)&W_px, (void*)&b_px,
    (void*)&W_pz, (void*)&b_pz,
    (void*)&W_pr, (void*)&b_pr,
    (void*)&W_en, (void*)&b_en,
    (void*)&W_de, (void*)&b_de,
    (void*)&W_ih, (void*)&W_hh,
    (void*)&b_ih, (void*)&b_hh,
    (void*)&ws, (void*)&out
  };
  hipLaunchCooperativeKernel((void*)mega_kernel, dim3(256), dim3(512),
                             kargs, 0, stream);
}

// Round 8
// 967.597 us; speedup vs baseline: 1.2997x; 1.2997x over previous
//
#include <hip/hip_runtime.h>
#include <math.h>

#define TT 96
#define BB 128
#define DD 800
#define LL 128

typedef _Float16 h2v __attribute__((ext_vector_type(2)));
typedef _Float16 f16x8 __attribute__((ext_vector_type(8)));
typedef float f32x4 __attribute__((ext_vector_type(4)));

// ---- ws layout (4B units), shared host/device ----
constexpr size_t O_WPX   = 0;                    // 102400 fp32
constexpr size_t O_WPR   = O_WPX   + 102400;     // 16384 uints (fdot2 pack)
constexpr size_t O_WEN   = O_WPR   + 16384;      // 16384 (out-half pack only)
constexpr size_t O_BFENX = O_WEN   + 32768;      // 16384 (MFMA B-frags W_en x-half)
constexpr size_t O_BFIZ  = O_BFENX + 16384;      // 32768 (MFMA B-frags W_ihz^T)
constexpr size_t O_BFHH  = O_BFIZ  + 32768;      // 32768 (MFMA B-frags W_hh^T)
constexpr size_t O_BFDE  = O_BFHH  + 32768;      // 102400 (MFMA B-frags W_de^T, K=256)
constexpr size_t O_BFPZ  = O_BFDE  + 102400;     // 8192 (MFMA B-frags W_pz^T)
constexpr size_t O_BL    = O_BFPZ  + 8192;       // 512
constexpr size_t O_ACC   = O_BL    + 512;        // 2 (double)
constexpr size_t O_PROG  = O_ACC   + 4;          // 128 ints (progress flags)
constexpr size_t O_XHAT  = O_PROG  + 128;        // (unused; layout keep)
constexpr size_t O_GX    = O_XHAT  + 786432;     // 6291456 fp32 (gxh: 12288 x 512)
constexpr size_t O_ENCX  = O_GX    + 6291456;    // 3145728 fp32 (encx: 12288 x 256)
constexpr size_t O_OUT   = O_ENCX  + 3145728;    // 1572864 fp32
constexpr size_t O_Q2    = O_OUT   + 1572864;    // float2[12288*128] (muq,sgq)
constexpr size_t O_P2    = O_Q2    + 3145728;    // float2[12288*128] (mup,sgp)

__device__ __forceinline__ h2v u2h(unsigned u) {
  union { unsigned u; h2v h; } x; x.u = u; return x.h;
}
__device__ __forceinline__ float fdot2(unsigned w, unsigned v, float acc) {
  return __builtin_amdgcn_fdot2(u2h(w), u2h(v), acc, false);
}
__device__ __forceinline__ unsigned packf16(float a, float b) {
  union { _Float16 h[2]; unsigned u; } x;
  x.h[0] = (_Float16)a; x.h[1] = (_Float16)b;
  return x.u;
}
__device__ __forceinline__ f16x8 u4h8(uint4 u) {
  union { uint4 u; f16x8 h; } x; x.u = u; return x.h;
}
__device__ __forceinline__ f32x4 mfma16(uint4 a, uint4 b, f32x4 c) {
  return __builtin_amdgcn_mfma_f32_16x16x32_f16(u4h8(a), u4h8(b), c, 0, 0, 0);
}
__device__ __forceinline__ float frcp(float x) { return __builtin_amdgcn_rcpf(x); }
__device__ __forceinline__ float fsigm(float x) { return frcp(1.f + __expf(-x)); }
__device__ __forceinline__ float ftanh(float x) {
  float e = __expf(2.f * fabsf(x));
  float t = 1.f - 2.f * frcp(e + 1.f);
  return copysignf(t, x);
}
__device__ __forceinline__ float hsum4(float4 a) { return (a.x + a.y) + (a.z + a.w); }

__device__ __forceinline__ void dotacc4(uint4 wv, uint4 vv, float4& av) {
  av.x = fdot2(wv.x, vv.x, av.x);
  av.y = fdot2(wv.y, vv.y, av.y);
  av.z = fdot2(wv.z, vv.z, av.z);
  av.w = fdot2(wv.w, vv.w, av.w);
}

// raw LDS-only barrier (no vmcnt drain); sched_barrier fences per rule #18
__device__ __forceinline__ void bar_lds() {
  asm volatile("s_waitcnt lgkmcnt(0)" ::: "memory");
  __builtin_amdgcn_sched_barrier(0);
  __builtin_amdgcn_s_barrier();
  __builtin_amdgcn_sched_barrier(0);
}

// agent-scope stores/loads for cross-XCD producer->consumer handoff
__device__ __forceinline__ void gstore(float* p, float v) {
  __hip_atomic_store(p, v, __ATOMIC_RELAXED, __HIP_MEMORY_SCOPE_AGENT);
}
__device__ __forceinline__ float gload(const float* p) {
  return __hip_atomic_load(p, __ATOMIC_RELAXED, __HIP_MEMORY_SCOPE_AGENT);
}
__device__ __forceinline__ void gstore2(float2* p, float a, float b) {
  union { float f[2]; unsigned long long u; } x; x.f[0] = a; x.f[1] = b;
  __hip_atomic_store((unsigned long long*)p, x.u, __ATOMIC_RELAXED, __HIP_MEMORY_SCOPE_AGENT);
}
__device__ __forceinline__ float2 gload2(const float2* p) {
  unsigned long long u = __hip_atomic_load((const unsigned long long*)p,
                                           __ATOMIC_RELAXED, __HIP_MEMORY_SCOPE_AGENT);
  union { unsigned long long u; float2 f; } x; x.u = u; return x.f;
}

// consumer LDS XOR swizzle (T2)
__device__ __forceinline__ int swz128(int row, int col) {
  return row * 128 + (col ^ ((row & 7) << 3));
}
__device__ __forceinline__ int swz256(int row, int col) {
  return row * 256 + (col ^ ((row & 7) << 3));
}

// ---------------- prep bodies (shared by prep_all) ----------------
__device__ __forceinline__ void pack_f16_body(const float* __restrict__ src,
                                              unsigned* __restrict__ dst,
                                              int J, int rs, int k0, int idx, int total) {
  if (idx >= total) return;
  int u = idx & 3;
  int t2 = idx >> 2;
  int k8 = t2 / J;
  int j = t2 - k8 * J;
  int k = k8 * 8 + u * 2;
  const float* r = src + (size_t)j * rs + k0 + k;
  dst[idx] = packf16(r[0], r[1]);
}

__device__ __forceinline__ void bfrag_body(const float* __restrict__ src,
                                           unsigned* __restrict__ dst,
                                           int rs, int k0, int KS, int mode,
                                           int idx, int total) {
  if (idx >= total) return;
  int jj = idx & 3;
  int lane = (idx >> 2) & 63;
  int t2 = idx >> 8;
  int ks = t2 % KS;
  int g = t2 / KS;
  int n = (mode == 0) ? (128 * (g & 3) + 16 * (g >> 2) + (lane & 15))
                      : (16 * g + (lane & 15));
  int k = ks * 32 + (lane >> 4) * 8 + jj * 2;
  const float* r = src + (size_t)n * rs + k0 + k;
  dst[idx] = packf16(r[0], r[1]);
}

__device__ __forceinline__ void transpose_body(const float* __restrict__ src,
                                               float* __restrict__ dst,
                                               int J, int rs, int k0, int idx, int total) {
  if (idx >= total) return;
  int J4 = J * 4;
  int k4 = idx / J4;
  int rem = idx - k4 * J4;
  int j = rem >> 2;
  int kk = rem & 3;
  dst[idx] = src[j * rs + k0 + k4 * 4 + kk];
}

// ---------------- prep_all: every weight transform in ONE launch ----------------
__global__ __launch_bounds__(256) void prep_all(
    const float* __restrict__ b_ih, const float* __restrict__ b_hh,
    const float* __restrict__ W_pr, const float* __restrict__ W_en,
    const float* __restrict__ W_ih, const float* __restrict__ W_hh,
    const float* __restrict__ W_pz, const float* __restrict__ W_de,
    const float* __restrict__ W_px, float* __restrict__ ws)
{
  int blk = blockIdx.x;
  const int tid = threadIdx.x;
  if (blk < 3) {
    if (blk < 2) {
      int i = blk * 256 + tid;
      ws[O_BL + i] = b_ih[i] + b_hh[i];
    } else {
      if (tid == 0) *(double*)(ws + O_ACC) = 0.0;
      if (tid < 128)
        __hip_atomic_store((int*)(ws + O_PROG) + tid, 0, __ATOMIC_RELAXED,
                           __HIP_MEMORY_SCOPE_AGENT);
    }
    return;
  }
  blk -= 3;
  if (blk < 64) { pack_f16_body(W_pr, (unsigned*)(ws + O_WPR), 256, 128, 0, blk * 256 + tid, 16384); return; }
  blk -= 64;
  if (blk < 64) { pack_f16_body(W_en, (unsigned*)(ws + O_WEN), 256, 256, 0, blk * 256 + tid, 16384); return; }
  blk -= 64;
  if (blk < 64) { bfrag_body(W_en, (unsigned*)(ws + O_BFENX), 256, 128, 4, 1, blk * 256 + tid, 16384); return; }
  blk -= 64;
  if (blk < 128) { bfrag_body(W_ih, (unsigned*)(ws + O_BFIZ), 256, 128, 4, 0, blk * 256 + tid, 32768); return; }
  blk -= 128;
  if (blk < 128) { bfrag_body(W_hh, (unsigned*)(ws + O_BFHH), 128, 0, 4, 0, blk * 256 + tid, 32768); return; }
  blk -= 128;
  if (blk < 32) { bfrag_body(W_pz, (unsigned*)(ws + O_BFPZ), 128, 0, 4, 1, blk * 256 + tid, 8192); return; }
  blk -= 32;
  if (blk < 400) { bfrag_body(W_de, (unsigned*)(ws + O_BFDE), 256, 0, 8, 1, blk * 256 + tid, 102400); return; }
  blk -= 400;
  transpose_body(W_px, ws + O_WPX, 128, 800, 0, blk * 256 + tid, 102400);
}

__device__ __forceinline__ float dot4(float4 w, float4 v) {
  return w.x*v.x + w.y*v.y + w.z*v.z + w.w*v.w;
}

// ---------------- xhat_gx: fused xhat tile -> gxh/encx (tile-local) ----------
// One 16-pair tile per block, 768 blocks. xhat GEMV with wave-uniform scalar x
// loads (g = tid>>7 is wave-uniform; readfirstlane pins the row offset to an
// SGPR) -> packed f16 tile in tiny LDS (4.4KB, so occupancy is VGPR-bound at
// ~6 waves/SIMD; R7's mega-merge ran this at 8 waves/CU under a 158KB LDS
// reservation and stalled) -> gxh (4 MFMA tiles/wave) + encx (2 tiles/wave).
// xhat2 never touches global: its only consumer is this block's gx step.
__global__ __launch_bounds__(512) void xhat_gx_kernel(
    const float* __restrict__ x, const float* __restrict__ Wpx4,
    const float* __restrict__ b_px,
    const uint4* __restrict__ BFihz, const uint4* __restrict__ BFenx,
    const float* __restrict__ b_lstm,
    float* __restrict__ gxh, float* __restrict__ encx)
{
  __shared__ __align__(16) unsigned s_xh[16 * 68];   // padded rows (4352B)
  const int tid = threadIdx.x;
  const int j = tid & 127, g = tid >> 7;   // g uniform per wave
  const int wv = tid >> 6, lane = tid & 63, l15 = lane & 15, quad = lane >> 4;
  const int p0 = blockIdx.x * 16;

  // xhat for rows g+4u: x addresses wave-uniform -> scalar (K$) loads
  int offs[4];
  #pragma unroll
  for (int u = 0; u < 4; ++u) {
    int p = p0 + g + 4 * u;
    int b_ = p & 127, t_ = p >> 7;
    offs[u] = __builtin_amdgcn_readfirstlane((b_ * TT + t_) * 800);
  }
  const float bj = b_px[j];
  float acc[4];
  #pragma unroll
  for (int u = 0; u < 4; ++u) acc[u] = bj;
  const float4* W = (const float4*)Wpx4;
  #pragma unroll 2
  for (int k4 = 0; k4 < 200; ++k4) {
    float4 w = W[k4 * 128 + j];
    #pragma unroll
    for (int u = 0; u < 4; ++u) {
      float4 xv = *(const float4*)(x + offs[u] + k4 * 4);
      acc[u] += dot4(w, xv);
    }
  }
  #pragma unroll
  for (int u = 0; u < 4; ++u) {
    float v = fmaxf(acc[u], 0.f);
    float vp = __shfl_xor(v, 1, 64);
    if ((j & 1) == 0)
      s_xh[(g + 4 * u) * 68 + (j >> 1)] = packf16(v, vp);
  }
  __syncthreads();

  // gx: A-frags from LDS tile; gxh 4 tiles + encx 2 tiles per wave
  uint4 a[4];
  #pragma unroll
  for (int ks = 0; ks < 4; ++ks)
    a[ks] = *(const uint4*)&s_xh[l15 * 68 + ks * 16 + quad * 4];
  #pragma unroll
  for (int nt = 0; nt < 4; ++nt) {
    int gg = wv * 4 + nt;
    int n = 128 * (gg & 3) + 16 * (gg >> 2) + l15;
    float bl = b_lstm[n];
    f32x4 acc2 = {0.f, 0.f, 0.f, 0.f};
    #pragma unroll
    for (int ks = 0; ks < 4; ++ks)
      acc2 = mfma16(a[ks], BFihz[(gg * 4 + ks) * 64 + lane], acc2);
    #pragma unroll
    for (int r = 0; r < 4; ++r)
      gxh[(size_t)(p0 + quad * 4 + r) * 512 + n] = acc2[r] + bl;
  }
  #pragma unroll
  for (int gt = 0; gt < 2; ++gt) {
    int gg = wv * 2 + gt;
    f32x4 acc2 = {0.f, 0.f, 0.f, 0.f};
    #pragma unroll
    for (int ks = 0; ks < 4; ++ks)
      acc2 = mfma16(a[ks], BFenx[(gg * 4 + ks) * 64 + lane], acc2);
    #pragma unroll
    for (int r = 0; r < 4; ++r)
      encx[(size_t)(p0 + quad * 4 + r) * 256 + 16 * gg + l15] = acc2[r];
  }
}

// ---------------- fused producer/consumer kernel (R6, unchanged) ----------------
__global__ __launch_bounds__(512) void fused_kernel(
    const float* __restrict__ eps,
    const uint4* __restrict__ Wpr4, const float* __restrict__ b_pr,
    const uint4* __restrict__ Wen4, const float* __restrict__ b_en,
    const uint4* __restrict__ BFpz, const float* __restrict__ b_pz,
    const uint4* __restrict__ BFihz, const uint4* __restrict__ BFhh,
    const float* __restrict__ gxh_g, const float* __restrict__ encx_g,
    float* __restrict__ g_out, float2* __restrict__ g_q2, float2* __restrict__ g_p2,
    const float* __restrict__ x, const float* __restrict__ beta_p,
    const uint4* __restrict__ BFde, const float* __restrict__ b_de,
    double* __restrict__ accum, int* __restrict__ prog)
{
  __shared__ __align__(16) char SMEM[161536];
  const int tid = threadIdx.x;

  if (blockIdx.x < 128) {
    // ================= producer: phase1 =================
    float* s_gz       = (float*)SMEM;               // [5120] gate pre-acts
    float* s_ehmu     = (float*)SMEM;               // [128] aliases gz[0:128]
    float* s_mup      = (float*)(SMEM + 512);       // [128]
    float* s_sgp      = (float*)(SMEM + 1024);      // [128]
    float* s_sgq      = (float*)(SMEM + 1536);      // [128]
    _Float16* s_z2    = (_Float16*)(SMEM + 20480);  // [16*136]
    _Float16* s_zh2   = (_Float16*)(SMEM + 24832);  // [16*136]
    float* s_out      = (float*)(SMEM + 29184);     // [128]
    unsigned* s_out2  = (unsigned*)(SMEM + 29696);  // [64]
    _Float16* s_h2    = (_Float16*)(SMEM + 29952);  // [2][128]
    uint4* s_bfihz    = (uint4*)(SMEM + 30464);     // [8192] (131072B)

    const int b = blockIdx.x;
    const int wv = tid >> 6;
    const int lane = tid & 63;
    const int l15 = lane & 15;
    const int quad = lane >> 4;

    // one-time: stage BFihz into LDS (16 uint4/thread, coalesced)
    #pragma unroll
    for (int i = 0; i < 16; ++i)
      s_bfihz[i * 512 + tid] = BFihz[i * 512 + tid];

    if (tid < 128) { s_out[tid] = 0.f; s_h2[tid] = (_Float16)0.f; }
    if (tid < 64) s_out2[tid] = 0u;
    float c_reg = 0.f;
    const float bias_pe = (tid < 256) ? b_pr[tid] : b_en[tid - 256];
    const float bz = b_pz[16 * wv + l15];
    const int gxoff = 16 * wv + l15;

    uint4 whhf[16], bfpz[4];
    #pragma unroll
    for (int i = 0; i < 16; ++i) whhf[i] = BFhh[(wv * 16 + i) * 64 + lane];
    #pragma unroll
    for (int ks = 0; ks < 4; ++ks) bfpz[ks] = BFpz[(wv * 4 + ks) * 64 + lane];

    // t=0 preloads (eps, gx, encx)
    float e0 = eps[(size_t)b * 1280 + tid];
    float e1 = eps[(size_t)b * 1280 + tid + 512];
    float e2 = (tid < 256) ? eps[(size_t)b * 1280 + tid + 1024] : 0.f;
    float gxf[4];
    #pragma unroll
    for (int nt = 0; nt < 4; ++nt)
      gxf[nt] = gxh_g[(size_t)b * 512 + 128 * nt + gxoff];
    float encx_r = (tid >= 256) ? encx_g[(size_t)b * 256 + (tid - 256)] : 0.f;

    __syncthreads();

    for (int t = 0; t < TT; ++t) {
      const size_t pb = (size_t)t * BB + b;

      // S1: prior (tid<256) / encoder (tid>=256) GEMV
      {
        float4 a4 = {bias_pe, 0.f, 0.f, 0.f};
        if (tid < 256) {
          #pragma unroll 4
          for (int k8 = 0; k8 < 16; ++k8) {
            uint4 w = Wpr4[k8 * 256 + tid];
            uint4 o = *(const uint4*)&s_out2[k8 * 4];
            dotacc4(w, o, a4);
          }
          float ph = fmaxf(hsum4(a4), 0.f);
          if (tid < 128) s_mup[tid] = ph;
          else {
            float y = __expf(ph) + 0.5f;
            float sp = (y > 20.f) ? y : __logf(1.f + __expf(y));
            s_sgp[tid - 128] = sp;
          }
        } else {
          int j2 = tid - 256;
          #pragma unroll 4
          for (int k8 = 0; k8 < 16; ++k8) {
            uint4 w = Wen4[k8 * 256 + j2];
            uint4 o = *(const uint4*)&s_out2[k8 * 4];
            dotacc4(w, o, a4);
          }
          float eh = fmaxf(hsum4(a4) + encx_r, 0.f);
          if (j2 < 128) s_ehmu[j2] = eh;
          else s_sgq[j2 - 128] = __expf(eh);
        }
      }
      bar_lds();                             // B2

      // S2: z into padded s_z2 rows (sample = row)
      {
        int l = tid & 127, s0 = tid >> 7;
        float mu = s_ehmu[l] + s_mup[l];
        float sq = s_sgq[l];
        s_z2[s0 * 136 + l]        = (_Float16)(mu + sq * e0);
        s_z2[(s0 + 4) * 136 + l]  = (_Float16)(mu + sq * e1);
        if (tid < 256) s_z2[(s0 + 8) * 136 + l] = (_Float16)(mu + sq * e2);
      }
      bar_lds();                             // B3

      // batched sc1 publication of timestep t; drains at B5's full sync
      if (tid < 128) {
        gstore2(&g_q2[pb * 128 + tid], s_ehmu[tid] + s_mup[tid], s_sgq[tid]);
      } else if (tid < 256) {
        gstore(&g_out[pb * 128 + tid - 128], s_out[tid - 128]);
      } else if (tid < 384) {
        int l = tid - 256;
        gstore2(&g_p2[pb * 128 + l], s_mup[l], s_sgp[l]);
      }

      // S3: z_hat via MFMA
      {
        uint4 a[4];
        #pragma unroll
        for (int ks = 0; ks < 4; ++ks)
          a[ks] = *(const uint4*)&s_z2[l15 * 136 + ks * 32 + quad * 8];
        f32x4 acc = {bz, bz, bz, bz};
        #pragma unroll
        for (int ks = 0; ks < 4; ++ks)
          acc = mfma16(a[ks], bfpz[ks], acc);
        #pragma unroll
        for (int r = 0; r < 4; ++r) {
          int s = quad * 4 + r;
          if (s < 10)
            s_zh2[s * 136 + 16 * wv + l15] = (_Float16)fmaxf(acc[r], 0.f);
        }
      }
      bar_lds();                             // B4

      // S4: gates-z via MFMA; B-frags from LDS, init from precomputed gxf
      {
        uint4 a[4];
        #pragma unroll
        for (int ks = 0; ks < 4; ++ks)
          a[ks] = *(const uint4*)&s_zh2[l15 * 136 + ks * 32 + quad * 8];
        #pragma unroll
        for (int nt = 0; nt < 4; ++nt) {
          float gx = gxf[nt];
          f32x4 acc = {gx, gx, gx, gx};
          #pragma unroll
          for (int ks = 0; ks < 4; ++ks)
            acc = mfma16(a[ks], s_bfihz[((wv * 4 + nt) * 4 + ks) * 64 + lane], acc);
          #pragma unroll
          for (int r = 0; r < 4; ++r) {
            int s = quad * 4 + r;
            if (s < 10)
              s_gz[s * 512 + 128 * nt + 16 * wv + l15] = acc[r];
          }
        }
      }
      __syncthreads();                       // B5 FULL: drains g_* sc1 stores + orders s_gz

      if (tid == 0)
        __hip_atomic_store(&prog[b], t + 1, __ATOMIC_RELAXED, __HIP_MEMORY_SCOPE_AGENT);

      // t+1 prefetch under the LSTM
      if (t + 1 < TT) {
        const float* epn = eps + (pb + BB) * 1280;
        e0 = epn[tid];
        e1 = epn[tid + 512];
        if (tid < 256) e2 = epn[tid + 1024];
        #pragma unroll
        for (int nt = 0; nt < 4; ++nt)
          gxf[nt] = gxh_g[(pb + BB) * 512 + 128 * nt + gxoff];
        if (tid >= 256) encx_r = encx_g[(pb + BB) * 256 + (tid - 256)];
      }

      // serial LSTM over 10 samples, double-buffered h
      float oacc = 0.f;
      for (int s = 0; s < 10; ++s) {
        const _Float16* hb = &s_h2[(s & 1) * 128];
        uint4 a[4];
        #pragma unroll
        for (int ks = 0; ks < 4; ++ks)
          a[ks] = *(const uint4*)&hb[ks * 32 + quad * 8];
        f32x4 acc[4];
        #pragma unroll
        for (int nt = 0; nt < 4; ++nt) {
          float cz = s_gz[s * 512 + 128 * nt + 16 * wv + l15];
          acc[nt] = f32x4{cz, cz, cz, cz};
        }
        #pragma unroll
        for (int nt = 0; nt < 4; ++nt)
          #pragma unroll
          for (int ks = 0; ks < 4; ++ks)
            acc[nt] = mfma16(a[ks], whhf[nt * 4 + ks], acc[nt]);
        if (lane < 16) {
          float gi = acc[0][0], gf = acc[1][0], gg = acc[2][0], go = acc[3][0];
          c_reg = fsigm(gf) * c_reg + fsigm(gi) * ftanh(gg);
          float h = fsigm(go) * ftanh(c_reg);
          oacc += h;
          s_h2[((s + 1) & 1) * 128 + 16 * wv + lane] = (_Float16)h;
        }
        if (s < 9) bar_lds();
      }
      if (lane < 16) {
        float v = oacc * 0.1f;
        s_out[16 * wv + lane] = v;
        float vn = __shfl_xor(v, 1, 64);
        if (!(lane & 1)) s_out2[8 * wv + (lane >> 1)] = packf16(v, vn);
      }
      bar_lds();
    }
  } else {
    // ================= consumer: phase2, MFMA + swizzled LDS =================
    _Float16* c_z2   = (_Float16*)SMEM;             // [48*128] swizzled
    _Float16* c_a2   = (_Float16*)(SMEM + 12288);   // [48*256] swizzled
    float* c_x       = (float*)(SMEM + 36864);      // [4*800]
    unsigned* c_out2 = (unsigned*)(SMEM + 49664);   // [256]
    float* c_muq     = (float*)(SMEM + 50688);      // [512]
    float* c_sgq     = (float*)(SMEM + 52736);
    float* c_mup     = (float*)(SMEM + 54784);
    float* c_sgp     = (float*)(SMEM + 56832);
    float* c_wred    = (float*)(SMEM + 58880);      // [8]

    const int cid = blockIdx.x - 128;
    const int wv = tid >> 6;
    const int lane = tid & 63;
    const int l15 = lane & 15;
    const int quad = lane >> 4;
    const float beta = beta_p[0];

    for (int c = cid; c < 3072; c += 128) {
      const int p0 = c * 4;
      const int t = p0 >> 7;
      const int b0 = p0 & 127;

      if (tid < 4) {
        while (__hip_atomic_load(&prog[b0 + tid], __ATOMIC_RELAXED,
                                 __HIP_MEMORY_SCOPE_AGENT) <= t)
          __builtin_amdgcn_s_sleep(8);
      }
      __syncthreads();

      float acc_loc = 0.f;
      {
        size_t gi = (size_t)p0 * 128 + tid;
        float2 q = gload2(&g_q2[gi]); c_muq[tid] = q.x; c_sgq[tid] = q.y;
        float2 pv = gload2(&g_p2[gi]); c_mup[tid] = pv.x; c_sgp[tid] = pv.y;
      }
      if (tid < 256) {
        int pair = tid >> 6, m = tid & 63;
        const float* o = g_out + (size_t)p0 * 128 + pair * 128;
        c_out2[tid] = packf16(gload(o + 2*m), gload(o + 2*m + 1));
      }
      for (int i = tid; i < 3200; i += 512) {
        int pp = i / 800;
        int d = i - pp * 800;
        int p = p0 + pp, bb = p & 127, tt2 = p >> 7;
        c_x[i] = x[((size_t)bb * TT + tt2) * 800 + d];
      }
      __syncthreads();

      // z + KL
      {
        int l = tid & 127, pp = tid >> 7;
        float mq = c_muq[pp*128 + l], sq = c_sgq[pp*128 + l];
        float mp = c_mup[pp*128 + l], spv = c_sgp[pp*128 + l];
        float inv_sp = frcp(spv);
        float lsq = __logf(sq), lsp = __logf(spv);
        const float* ep = eps + (size_t)(p0 + pp) * 1280 + l;
        float kl = 0.f;
        #pragma unroll
        for (int s = 0; s < 10; ++s) {
          float e = ep[s * 128];
          float z = mq + sq * e;
          c_z2[swz128(pp * 10 + s, l)] = (_Float16)z;
          float ap = (z - mp) * inv_sp;
          kl += (-0.5f * e * e - lsq) - (-0.5f * ap * ap - lsp);
        }
        acc_loc -= beta * kl;
      }
      for (int i = tid; i < 2560; i += 512) {
        int r = i >> 6, m = i & 63;
        int pp = (r * 205) >> 11;
        ((unsigned*)c_a2)[r * 128 + 64 + (m ^ ((r & 7) << 2))] = c_out2[pp * 64 + m];
      }
      __syncthreads();

      // z_hat via MFMA: M=48(40 used) N=128 K=128
      for (int tile = wv; tile < 24; tile += 8) {
        int mt = tile >> 3, nt = tile & 7;
        uint4 a[4];
        #pragma unroll
        for (int ks = 0; ks < 4; ++ks)
          a[ks] = *(const uint4*)&c_z2[swz128(mt * 16 + l15, ks * 32 + quad * 8)];
        float bzt = b_pz[16 * nt + l15];
        f32x4 acc = {bzt, bzt, bzt, bzt};
        #pragma unroll
        for (int ks = 0; ks < 4; ++ks)
          acc = mfma16(a[ks], BFpz[(nt * 4 + ks) * 64 + lane], acc);
        #pragma unroll
        for (int r = 0; r < 4; ++r) {
          int row = mt * 16 + quad * 4 + r;
          c_a2[swz256(row, 16 * nt + l15)] = (_Float16)fmaxf(acc[r], 0.f);
        }
      }
      __syncthreads();

      // decoder GEMM + Bernoulli epilogue
      #pragma unroll
      for (int mt = 0; mt < 3; ++mt) {
        uint4 a[8];
        #pragma unroll
        for (int ks = 0; ks < 8; ++ks)
          a[ks] = *(const uint4*)&c_a2[swz256(mt * 16 + l15, ks * 32 + quad * 8)];
        for (int nt = wv; nt < 50; nt += 8) {
          f32x4 acc = {0.f, 0.f, 0.f, 0.f};
          #pragma unroll
          for (int ks = 0; ks < 8; ++ks)
            acc = mfma16(a[ks], BFde[(nt * 8 + ks) * 64 + lane], acc);
          int d = 16 * nt + l15;
          float bd = b_de[d];
          #pragma unroll
          for (int r = 0; r < 4; ++r) {
            int row = mt * 16 + quad * 4 + r;
            if (row < 40) {
              int pp = (row * 205) >> 11;
              float lg = fmaxf(acc[r] + bd, 0.f);
              float xd = c_x[pp * 800 + d];
              acc_loc += xd * lg - lg - __logf(1.f + __expf(-lg));
            }
          }
        }
      }

      float v = acc_loc;
      #pragma unroll
      for (int off = 32; off > 0; off >>= 1) v += __shfl_down(v, off, 64);
      if ((tid & 63) == 0) c_wred[tid >> 6] = v;
      __syncthreads();
      if (tid == 0) {
        double tot = 0.0;
        #pragma unroll
        for (int w = 0; w < 8; ++w) tot += (double)c_wred[w];
        atomicAdd(accum, tot);
      }
      __syncthreads();
    }
  }
}

__global__ void finalize_kernel(const double* __restrict__ accum, float* __restrict__ out) {
  if (threadIdx.x == 0 && blockIdx.x == 0)
    out[0] = (float)(-accum[0] / 122880.0);   // B*T*S
}

// ---------------- host ----------------
extern "C" void kernel_launch(void* const* d_in, const int* in_sizes, int n_in,
                              void* d_out, int out_size, void* d_ws, size_t ws_size,
                              hipStream_t stream) {
  const float* x    = (const float*)d_in[0];
  const float* beta = (const float*)d_in[1];
  const float* eps  = (const float*)d_in[2];
  const float* W_px = (const float*)d_in[3];
  const float* b_px = (const float*)d_in[4];
  const float* W_pz = (const float*)d_in[5];
  const float* b_pz = (const float*)d_in[6];
  const float* W_pr = (const float*)d_in[7];
  const float* b_pr = (const float*)d_in[8];
  const float* W_en = (const float*)d_in[9];
  const float* b_en = (const float*)d_in[10];
  const float* W_de = (const float*)d_in[11];
  const float* b_de = (const float*)d_in[12];
  const float* W_ih = (const float*)d_in[13];
  const float* W_hh = (const float*)d_in[14];
  const float* b_ih = (const float*)d_in[15];
  const float* b_hh = (const float*)d_in[16];
  float* ws = (float*)d_ws;

  // 1: all weight transforms in one launch
  prep_all<<<dim3(1283), dim3(256), 0, stream>>>(
      b_ih, b_hh, W_pr, W_en, W_ih, W_hh, W_pz, W_de, W_px, ws);

  // 2: fused xhat -> gxh/encx (tile-local, high-occupancy standalone)
  xhat_gx_kernel<<<dim3(768), dim3(512), 0, stream>>>(
      x, ws + O_WPX, b_px,
      (const uint4*)(ws + O_BFIZ), (const uint4*)(ws + O_BFENX),
      ws + O_BL, ws + O_GX, ws + O_ENCX);

  // 3: fused cooperative producer/consumer launch
  {
    const uint4* Wpr4  = (const uint4*)(ws + O_WPR);
    const uint4* Wen4  = (const uint4*)(ws + O_WEN);
    const uint4* BFpz  = (const uint4*)(ws + O_BFPZ);
    const uint4* BFihz = (const uint4*)(ws + O_BFIZ);
    const uint4* BFhh  = (const uint4*)(ws + O_BFHH);
    const uint4* BFde  = (const uint4*)(ws + O_BFDE);
    const float* gxh   = ws + O_GX;
    const float* encx  = ws + O_ENCX;
    float* g_out = ws + O_OUT;
    float2* g_q2 = (float2*)(ws + O_Q2);
    float2* g_p2 = (float2*)(ws + O_P2);
    double* accum = (double*)(ws + O_ACC);
    int* prog = (int*)(ws + O_PROG);

    void* kargs[] = {
      (void*)&eps,
      (void*)&Wpr4, (void*)&b_pr, (void*)&Wen4, (void*)&b_en,
      (void*)&BFpz, (void*)&b_pz, (void*)&BFihz, (void*)&BFhh,
      (void*)&gxh, (void*)&encx,
      (void*)&g_out, (void*)&g_q2, (void*)&g_p2,
      (void*)&x, (void*)&beta,
      (void*)&BFde, (void*)&b_de,
      (void*)&accum, (void*)&prog
    };
    hipLaunchCooperativeKernel((void*)fused_kernel, dim3(256), dim3(512),
                               kargs, 0, stream);
  }

  // 4: finalize
  finalize_kernel<<<dim3(1), dim3(64), 0, stream>>>((const double*)(ws + O_ACC), (float*)d_out);
}